// Round 2
// baseline (146.045 us; speedup 1.0000x reference)
//
#include <hip/hip_runtime.h>
#include <float.h>
#include <math.h>

#define NSAMPLE 8192
#define KSEL 9          // K+1: keep 9 smallest incl. self
#define KNN 8
#define BLK 512
#define EPS_F 1e-12f

#define ROWS_PB 8                    // rows per block -> 1024 blocks
#define NBLOCKS (NSAMPLE / ROWS_PB)  // 1024
#define RPT 8                        // R18: ALL 8 rows per thread
#define LANES 64
#define KQT 16                       // scan iters per wave (1024-cand octant / 64)
#define BNDI 4                       // bound iters per wave (256 of the octant)
#define BATCH 4
#define WCAP 32                      // survivor cap per (wave,row) list
#define BP 129                       // bound minima stride (128 + 1 pad)
#define IDX_MASK 0x1FFFu             // low 13 bits = candidate index
#define VAL_MASK 0xFFFFE000u         // high 19 bits = d2 (sign+exp+10 mantissa)
#define PROW 73                      // merge-row stride (72 + 1 pad)
#define SROW 145                     // scratch stride (16*9 + 1)
#define SCALE (1.0f / (float)(NSAMPLE * KNN * 3))

__device__ __forceinline__ unsigned umn(unsigned a, unsigned b) { return a < b ? a : b; }
__device__ __forceinline__ unsigned umx(unsigned a, unsigned b) { return a > b ? a : b; }

// Branchless insert of x into descending-sorted s[0..8] (s[0]=worst, s[8]=best).
__device__ __forceinline__ void insert9(unsigned s[KSEL], unsigned x)
{
#pragma unroll
    for (int k = 0; k < KSEL - 1; ++k)
        s[k] = umx(s[k + 1], umn(x, s[k]));
    s[KSEL - 1] = umn(x, s[KSEL - 1]);
}

// Packed (d2 | idx). d2 clamped >= 0 so self packs minimal.
__device__ __forceinline__ unsigned pack_d2(float d2, int gidx)
{
    return (__float_as_uint(fmaxf(d2, 0.0f)) & VAL_MASK) | (unsigned)gidx;
}

// Force a wave-uniform float into an SGPR (frees per-lane VGPR copies).
__device__ __forceinline__ float sfl(float x)
{
    return __uint_as_float((unsigned)__builtin_amdgcn_readfirstlane(
        (int)__float_as_uint(x)));
}

// popcount(mask & lanes_below_me) in 2 VALU (v_mbcnt_lo/hi).
__device__ __forceinline__ unsigned mbcnt64(unsigned long long m)
{
    return __builtin_amdgcn_mbcnt_hi((unsigned)(m >> 32),
           __builtin_amdgcn_mbcnt_lo((unsigned)(m & 0xFFFFFFFFull), 0u));
}

// ---------------------------------------------------------------------------
// Kernel 1: one-time gather into compact L2-resident float4 arrays:
//   sm4 = (mean.xyz, |mean|^2), ss4 = (sh0.xyz, 0).
// ---------------------------------------------------------------------------
__global__ __launch_bounds__(256) void gather_k(
    const float* __restrict__ means, const float* __restrict__ sh0,
    const int* __restrict__ idx,
    float4* __restrict__ sm4, float4* __restrict__ ss4)
{
    int i = blockIdx.x * 256 + threadIdx.x;
    if (i >= NSAMPLE) return;
    int id = idx[i];
    const float* m = means + 3 * id;
    const float* s = sh0 + 3 * id;
    float mx = m[0], my = m[1], mz = m[2];
    sm4[i] = make_float4(mx, my, mz, fmaf(mx, mx, fmaf(my, my, mz * mz)));
    ss4[i] = make_float4(s[0], s[1], s[2], 0.0f);
}

// ---------------------------------------------------------------------------
// Kernel 2 (R18): RPT 4 -> 8. R17's VALU cuts barely moved the total =>
// main_k is load-latency/L1-bound, not issue-bound. The invariant across
// R11-R17 was 40 float4 loads/lane (each 16B candidate feeding only 4 rows).
// Now each wave computes ALL 8 block-rows against its own 1024-cand OCTANT:
//   - candidate loads/lane: 40 -> 20 (traffic halved grid-wide)
//   - fma total, ballot total, wave count, occupancy: unchanged
//   - per-batch compute (4 groups x 24 fma ~ 240cy) now covers L2 latency,
//     so the ping-pong prefetch actually hides the stream.
// Bound: 8 octant slices of 256 cands (same 2048-sample quality as before),
// 2-level __shfl_xor fold -> 128 minima/row keeps LDS < 20 KB (4 blocks/CU).
// Survivors: 64 (wave,row) lists, lambda ~4.5 each (was 9) -> WCAP safer.
// Screen/packing/dup semantics bit-inherited from R17 -> selection exact.
// ---------------------------------------------------------------------------
#define PROCESS(QR, KB)                                                       \
    {                                                                         \
        _Pragma("unroll")                                                     \
        for (int u = 0; u < BATCH; ++u) {                                     \
            float sv[RPT];                                                    \
            _Pragma("unroll")                                                 \
            for (int i = 0; i < RPT; ++i)                                     \
                sv[i] = fmaf(cX[i], QR[u].x, fmaf(cY[i], QR[u].y,             \
                        fmaf(cZ[i], QR[u].z, QR[u].w)));                      \
            unsigned long long mk[RPT];                                       \
            _Pragma("unroll")                                                 \
            for (int i = 0; i < RPT; ++i)                                     \
                mk[i] = __ballot(sv[i] <= sb[i]);                             \
            const int ci = s0 + ((KB) + u) * LANES + lane;                    \
            _Pragma("unroll")                                                 \
            for (int i = 0; i < RPT; ++i) {                                   \
                if (mk[i]) {                    /* scalar-uniform, ~25% */    \
                    unsigned pos = base[i] + mbcnt64(mk[i]);                  \
                    if ((sv[i] <= sb[i]) && pos < WCAP)                       \
                        wl[(w * RPT + i) * WCAP + pos] =                      \
                            pack_d2(sv[i] + cW[i], ci);                       \
                    base[i] += (unsigned)__popcll(mk[i]);                     \
                }                                                             \
            }                                                                 \
        }                                                                     \
    }

__global__ __launch_bounds__(BLK, 8) void main_k(
    const float4* __restrict__ sm4, const float4* __restrict__ ss4,
    float* __restrict__ partial)
{
    __shared__ unsigned wl[8 * RPT * WCAP];       // 8 KB private survivor lists
    __shared__ unsigned wcnt[8 * RPT];
    __shared__ unsigned bpart[ROWS_PB * BP];      // 4.1 KB bound minima (folded)
    __shared__ unsigned scratch[ROWS_PB * SROW];  // 4.6 KB bound-merge scratch
    __shared__ unsigned partS[ROWS_PB * PROW];    // 2.3 KB merge scratch 2
    __shared__ unsigned bnd[ROWS_PB];
    __shared__ float    red[ROWS_PB];

    const int t = threadIdx.x;
    const int lane = t & (LANES - 1);
    const int w = t >> 6;                       // 0..7 (wave id = octant)

    // Own-row coefficients -> SGPRs (wave-uniform; canonical d2 = s + cW
    // where s = fmaf(cX,qx, fmaf(cY,qy, fmaf(cZ,qz, qw)))).
    float cX[RPT], cY[RPT], cZ[RPT], cW[RPT];
#pragma unroll
    for (int i = 0; i < RPT; ++i) {
        float4 p = sm4[blockIdx.x * ROWS_PB + i];
        cX[i] = sfl(-2.0f * p.x);
        cY[i] = sfl(-2.0f * p.y);
        cZ[i] = sfl(-2.0f * p.z);
        cW[i] = sfl(p.w);
    }

    // ---- Bound: per-lane packed min over 4-cand slices of the octant's
    // first 256 cands (8 octants -> 2048-cand sample). Fold lanes ^32,^16
    // -> 128 minima/row (each the min of 16 distinct candidates).
    {
        unsigned pm[RPT];
#pragma unroll
        for (int i = 0; i < RPT; ++i) pm[i] = 0xFFFFFFFFu;
        const int b0 = w * (KQT * LANES);
#pragma unroll
        for (int k = 0; k < BNDI; ++k) {
            const int ci = b0 + k * LANES + lane;
            float4 q = sm4[ci];                 // coalesced, L1/L2-hot
#pragma unroll
            for (int i = 0; i < RPT; ++i) {
                float s = fmaf(cX[i], q.x,
                          fmaf(cY[i], q.y, fmaf(cZ[i], q.z, q.w)));
                pm[i] = umn(pm[i], pack_d2(s + cW[i], ci));  // canonical d2
            }
        }
#pragma unroll
        for (int i = 0; i < RPT; ++i) {
            pm[i] = umn(pm[i], (unsigned)__shfl_xor((int)pm[i], 32, 64));
            pm[i] = umn(pm[i], (unsigned)__shfl_xor((int)pm[i], 16, 64));
        }
        if (lane < 16) {
#pragma unroll
            for (int i = 0; i < RPT; ++i)
                bpart[i * BP + w * 16 + lane] = pm[i];
        }
    }
    __syncthreads();

    // Merge 128 minima/row -> bnd = 9th smallest (valid upper bound on the
    // row's true 9th: the 9 minima below it are 9 distinct candidates).
    if (t < 128) {                              // stage 1: 8 rows x 16 groups
        const int r1 = t & (ROWS_PB - 1);
        const int g = t >> 3;                   // 0..15
        unsigned s[KSEL];
#pragma unroll
        for (int k = 0; k < KSEL; ++k) s[k] = 0xFFFFFFFFu;
#pragma unroll
        for (int e = 0; e < 8; ++e)
            insert9(s, bpart[r1 * BP + g * 8 + e]);
#pragma unroll
        for (int k = 0; k < KSEL; ++k)
            scratch[r1 * SROW + g * KSEL + k] = s[k];
    }
    __syncthreads();
    if (t < 64) {                               // stage 2: 8 rows x 8 groups
        const int r1 = t & (ROWS_PB - 1);
        const int mg = t >> 3;                  // 0..7
        unsigned m[KSEL];
#pragma unroll
        for (int k = 0; k < KSEL; ++k) m[k] = 0xFFFFFFFFu;
#pragma unroll
        for (int e = 0; e < 2 * KSEL; ++e)
            insert9(m, scratch[r1 * SROW + (2 * mg) * KSEL + e]);
#pragma unroll
        for (int k = 0; k < KSEL; ++k)
            partS[r1 * PROW + mg * KSEL + k] = m[k];
    }
    __syncthreads();
    if (t < ROWS_PB) {                          // stage 3: 72 -> 9th
        unsigned m[KSEL];
#pragma unroll
        for (int k = 0; k < KSEL; ++k) m[k] = 0xFFFFFFFFu;
#pragma unroll
        for (int e = 0; e < 8 * KSEL; ++e)
            insert9(m, partS[t * PROW + e]);
        bnd[t] = m[0];
    }
    __syncthreads();

    // s-space screen bound: pack(d2)|idx <= b requires d2 <= bf where
    // bf = uint_as_float(b | IDX_MASK) (positive floats: uint order == float
    // order). d2 = fl(s + cW) <= bf  ==>  s <= (bf - cW) + ~ulp slack; the
    // relative loosening (on bf AND the difference) keeps sb a superset
    // bound under all cancellation cases. Extras are harmless.
    float sb[RPT];
#pragma unroll
    for (int i = 0; i < RPT; ++i) {
        float bfv = __uint_as_float(bnd[i] | IDX_MASK);
        float D = bfv - cW[i];
        sb[i] = sfl(D + (bfv + fabsf(D)) * 6.0e-7f + 1e-33f);
    }

    // ---- Scan: each wave sweeps its 1024-cand octant for all 8 rows ------
    unsigned base[RPT];
#pragma unroll
    for (int i = 0; i < RPT; ++i) base[i] = 0u;

    const int s0 = w * (KQT * LANES);
    const float4* __restrict__ qp = sm4 + s0 + lane;

    float4 qa[BATCH], qb[BATCH];
#pragma unroll
    for (int u = 0; u < BATCH; ++u) qa[u] = qp[u * LANES];

    for (int k0 = 0; k0 < KQT; k0 += 2 * BATCH) {
#pragma unroll
        for (int u = 0; u < BATCH; ++u)         // prefetch odd batch
            qb[u] = qp[(k0 + BATCH + u) * LANES];
        PROCESS(qa, k0)
        if (k0 + 2 * BATCH < KQT) {
#pragma unroll
            for (int u = 0; u < BATCH; ++u)     // prefetch next even batch
                qa[u] = qp[(k0 + 2 * BATCH + u) * LANES];
        }
        PROCESS(qb, k0 + BATCH)
    }
    if (lane == 0) {
#pragma unroll
        for (int i = 0; i < RPT; ++i)
            wcnt[w * RPT + i] = umn(base[i], WCAP);
    }
    __syncthreads();                             // survivor lists complete

    // ---- Select: 64 tasks, each merges one (wave,row) list ---------------
    if (t < 64) {
        const int r1 = t & (ROWS_PB - 1);        // row
        const int wv = t >> 3;                   // 0..7 octant wave
        const int li = wv * RPT + r1;
        const unsigned n = wcnt[li];
        unsigned s[KSEL];
#pragma unroll
        for (int k = 0; k < KSEL; ++k) s[k] = 0xFFFFFFFFu;
        for (unsigned k = 0; k < n; ++k)
            insert9(s, wl[li * WCAP + k]);
#pragma unroll
        for (int k = 0; k < KSEL; ++k)
            partS[r1 * PROW + wv * KSEL + k] = s[k];
    }
    __syncthreads();

    if (t < ROWS_PB) {                          // final 72-merge + epilogue
        unsigned m[KSEL];
#pragma unroll
        for (int k = 0; k < KSEL; ++k) m[k] = 0xFFFFFFFFu;
#pragma unroll
        for (int e = 0; e < 8 * KSEL; ++e)
            insert9(m, partS[t * PROW + e]);

        // m[8] = global min (self, or identical-coordinate dup whose term is
        // 0 either way) -> dropped. m[0..7] = the 8 neighbors.
        const int gr = blockIdx.x * ROWS_PB + t;
        float4 pm4 = sm4[gr];
        float4 ps4 = ss4[gr];
        float acc = 0.0f;
#pragma unroll
        for (int k = 0; k < KNN; ++k) {
            int j = (int)(m[k] & IDX_MASK);
            float4 qm = sm4[j];
            float dx = pm4.x - qm.x, dy = pm4.y - qm.y, dz = pm4.z - qm.z;
            float d2 = fmaf(dx, dx, fmaf(dy, dy, dz * dz));
            float d = sqrtf(fmaxf(d2, EPS_F));
            float wgt = expf(-d);
            float4 qs = ss4[j];
            float ax = ps4.x - qs.x, ay = ps4.y - qs.y, az = ps4.z - qs.z;
            acc += wgt * (ax * ax + ay * ay + az * az);
        }
        red[t] = acc;
    }
    __syncthreads();
    if (t == 0) {
        float ssum = 0.0f;
#pragma unroll
        for (int i = 0; i < ROWS_PB; ++i) ssum += red[i];
        partial[blockIdx.x] = ssum;              // plain store
    }
}

// ---------------------------------------------------------------------------
// Kernel 3: reduce 1024 block partials -> scalar (cost ~0, proven R15;
// kept deterministic/order-identical so the output stays bit-exact).
// ---------------------------------------------------------------------------
__global__ __launch_bounds__(256) void reduce_k(
    const float* __restrict__ partial, float* __restrict__ out)
{
    __shared__ float sbuf[4];
    int t = threadIdx.x;
    float v = 0.0f;
    for (int i = t; i < NBLOCKS; i += 256) v += partial[i];
    for (int off = 32; off > 0; off >>= 1) v += __shfl_down(v, off);
    if ((t & 63) == 0) sbuf[t >> 6] = v;
    __syncthreads();
    if (t == 0) {
        float s = sbuf[0] + sbuf[1] + sbuf[2] + sbuf[3];
        out[0] = s * SCALE;
    }
}

// ---------------------------------------------------------------------------
extern "C" void kernel_launch(void* const* d_in, const int* in_sizes, int n_in,
                              void* d_out, int out_size, void* d_ws, size_t ws_size,
                              hipStream_t stream)
{
    const float* means = (const float*)d_in[0];
    const float* sh0   = (const float*)d_in[1];
    const int*   idxp  = (const int*)d_in[2];

    float4* sm4 = (float4*)d_ws;                 // 128 KB
    float4* ss4 = sm4 + NSAMPLE;                 // 128 KB
    float*  partial = (float*)(ss4 + NSAMPLE);   // 4 KB

    gather_k<<<NSAMPLE / 256, 256, 0, stream>>>(means, sh0, idxp, sm4, ss4);
    main_k<<<NBLOCKS, BLK, 0, stream>>>(sm4, ss4, partial);
    reduce_k<<<1, 256, 0, stream>>>(partial, (float*)d_out);
}

// Round 3
// 98.109 us; speedup vs baseline: 1.4886x; 1.4886x over previous
//
#include <hip/hip_runtime.h>
#include <float.h>
#include <math.h>

#define NSAMPLE 8192
#define KSEL 9          // K+1: keep 9 smallest incl. self
#define KNN 8
#define BLK 512
#define EPS_F 1e-12f

#define ROWS_PB 8                    // rows per block -> 1024 blocks
#define NBLOCKS (NSAMPLE / ROWS_PB)  // 1024
#define RPT 8                        // all 8 rows per thread (octant scan)
#define LANES 64
#define KQT 16                       // scan iters per wave (1024-cand octant / 64)
#define BNDI 4                       // bound iters per wave (256 of the octant)
#define WCAP 32                      // survivor cap per (wave,row) list
#define BP 129                       // bound minima stride (128 + 1 pad)
#define IDX_MASK 0x1FFFu             // low 13 bits = candidate index
#define VAL_MASK 0xFFFFE000u         // high 19 bits = d2 (sign+exp+10 mantissa)
#define PROW 73                      // merge-row stride (72 + 1 pad)
#define SROW 145                     // scratch stride (16*9 + 1)
#define SCALE (1.0f / (float)(NSAMPLE * KNN * 3))

__device__ __forceinline__ unsigned umn(unsigned a, unsigned b) { return a < b ? a : b; }
__device__ __forceinline__ unsigned umx(unsigned a, unsigned b) { return a > b ? a : b; }

// Branchless insert of x into descending-sorted s[0..8] (s[0]=worst, s[8]=best).
__device__ __forceinline__ void insert9(unsigned s[KSEL], unsigned x)
{
#pragma unroll
    for (int k = 0; k < KSEL - 1; ++k)
        s[k] = umx(s[k + 1], umn(x, s[k]));
    s[KSEL - 1] = umn(x, s[KSEL - 1]);
}

// Packed (d2 | idx). d2 clamped >= 0 so self packs minimal.
__device__ __forceinline__ unsigned pack_d2(float d2, int gidx)
{
    return (__float_as_uint(fmaxf(d2, 0.0f)) & VAL_MASK) | (unsigned)gidx;
}

// Force a wave-uniform float into an SGPR (frees per-lane VGPR copies).
__device__ __forceinline__ float sfl(float x)
{
    return __uint_as_float((unsigned)__builtin_amdgcn_readfirstlane(
        (int)__float_as_uint(x)));
}

// popcount(mask & lanes_below_me) in 2 VALU (v_mbcnt_lo/hi).
__device__ __forceinline__ unsigned mbcnt64(unsigned long long m)
{
    return __builtin_amdgcn_mbcnt_hi((unsigned)(m >> 32),
           __builtin_amdgcn_mbcnt_lo((unsigned)(m & 0xFFFFFFFFull), 0u));
}

// ---------------------------------------------------------------------------
// Kernel 1: one-time gather into compact L2-resident float4 arrays:
//   sm4 = (mean.xyz, |mean|^2), ss4 = (sh0.xyz, 0).
// ---------------------------------------------------------------------------
__global__ __launch_bounds__(256) void gather_k(
    const float* __restrict__ means, const float* __restrict__ sh0,
    const int* __restrict__ idx,
    float4* __restrict__ sm4, float4* __restrict__ ss4)
{
    int i = blockIdx.x * 256 + threadIdx.x;
    if (i >= NSAMPLE) return;
    int id = idx[i];
    const float* m = means + 3 * id;
    const float* s = sh0 + 3 * id;
    float mx = m[0], my = m[1], mz = m[2];
    sm4[i] = make_float4(mx, my, mz, fmaf(mx, mx, fmaf(my, my, mz * mz)));
    ss4[i] = make_float4(s[0], s[1], s[2], 0.0f);
}

// ---------------------------------------------------------------------------
// Kernel 2 (R19): R18's RPT=8 octant structure (each wave sweeps its own
// 1024-cand octant for ALL 8 block rows -> candidate loads/lane 40 -> 20),
// with the R18 spill catastrophe fixed. R18 post-mortem: FETCH 43MB +
// WRITE 55MB per dispatch at VGPR_Count=32 = arrays demoted to scratch
// (giant PROCESS body stopped full unroll -> runtime indices -> rule-#20
// demotion). R19 codegen fixes:
//   1. QUAD macro: named scalars v0..v3 / m0..m3, compile-time row indexes
//      only -- nothing demotable.
//   2. Prefetch depth 2 (qa/qb, one float4 each): 8 VGPRs of buffer, not 32.
//      24 fma/candidate x 6 waves/SIMD covers L2 latency without depth 4.
//   3. #pragma unroll 1 on the k0 loop caps body size so inner unrolls
//      always complete.
//   4. __launch_bounds__(512,6): ~80-VGPR cap, 3 blocks/CU -- headroom vs
//      the 64-cap spill cliff.
// Screen/packing/dup semantics bit-inherited from R17 -> selection exact.
// ---------------------------------------------------------------------------
// Process rows R..R+3 (R = literal 0 or 4) of one candidate register Q.
#define QUAD(R, Q, CI)                                                        \
    {                                                                         \
        float v0 = fmaf(cX[(R) + 0], (Q).x, fmaf(cY[(R) + 0], (Q).y,          \
                   fmaf(cZ[(R) + 0], (Q).z, (Q).w)));                         \
        float v1 = fmaf(cX[(R) + 1], (Q).x, fmaf(cY[(R) + 1], (Q).y,          \
                   fmaf(cZ[(R) + 1], (Q).z, (Q).w)));                         \
        float v2 = fmaf(cX[(R) + 2], (Q).x, fmaf(cY[(R) + 2], (Q).y,          \
                   fmaf(cZ[(R) + 2], (Q).z, (Q).w)));                         \
        float v3 = fmaf(cX[(R) + 3], (Q).x, fmaf(cY[(R) + 3], (Q).y,          \
                   fmaf(cZ[(R) + 3], (Q).z, (Q).w)));                         \
        unsigned long long m0 = __ballot(v0 <= sb[(R) + 0]);                  \
        unsigned long long m1 = __ballot(v1 <= sb[(R) + 1]);                  \
        unsigned long long m2 = __ballot(v2 <= sb[(R) + 2]);                  \
        unsigned long long m3 = __ballot(v3 <= sb[(R) + 3]);                  \
        if (m0) {                                                             \
            unsigned pos = base[(R) + 0] + mbcnt64(m0);                       \
            if ((v0 <= sb[(R) + 0]) && pos < WCAP)                            \
                wl[(w * RPT + (R) + 0) * WCAP + pos] =                        \
                    pack_d2(v0 + cW[(R) + 0], (CI));                          \
            base[(R) + 0] += (unsigned)__popcll(m0);                          \
        }                                                                     \
        if (m1) {                                                             \
            unsigned pos = base[(R) + 1] + mbcnt64(m1);                       \
            if ((v1 <= sb[(R) + 1]) && pos < WCAP)                            \
                wl[(w * RPT + (R) + 1) * WCAP + pos] =                        \
                    pack_d2(v1 + cW[(R) + 1], (CI));                          \
            base[(R) + 1] += (unsigned)__popcll(m1);                          \
        }                                                                     \
        if (m2) {                                                             \
            unsigned pos = base[(R) + 2] + mbcnt64(m2);                       \
            if ((v2 <= sb[(R) + 2]) && pos < WCAP)                            \
                wl[(w * RPT + (R) + 2) * WCAP + pos] =                        \
                    pack_d2(v2 + cW[(R) + 2], (CI));                          \
            base[(R) + 2] += (unsigned)__popcll(m2);                          \
        }                                                                     \
        if (m3) {                                                             \
            unsigned pos = base[(R) + 3] + mbcnt64(m3);                       \
            if ((v3 <= sb[(R) + 3]) && pos < WCAP)                            \
                wl[(w * RPT + (R) + 3) * WCAP + pos] =                        \
                    pack_d2(v3 + cW[(R) + 3], (CI));                          \
            base[(R) + 3] += (unsigned)__popcll(m3);                          \
        }                                                                     \
    }

__global__ __launch_bounds__(BLK, 6) void main_k(
    const float4* __restrict__ sm4, const float4* __restrict__ ss4,
    float* __restrict__ partial)
{
    __shared__ unsigned wl[8 * RPT * WCAP];       // 8 KB private survivor lists
    __shared__ unsigned wcnt[8 * RPT];
    __shared__ unsigned bpart[ROWS_PB * BP];      // 4.1 KB bound minima (folded)
    __shared__ unsigned scratch[ROWS_PB * SROW];  // 4.6 KB bound-merge scratch
    __shared__ unsigned partS[ROWS_PB * PROW];    // 2.3 KB merge scratch 2
    __shared__ unsigned bnd[ROWS_PB];
    __shared__ float    red[ROWS_PB];

    const int t = threadIdx.x;
    const int lane = t & (LANES - 1);
    const int w = t >> 6;                       // 0..7 (wave id = octant)

    // Own-row coefficients -> SGPRs (wave-uniform; canonical d2 = s + cW
    // where s = fmaf(cX,qx, fmaf(cY,qy, fmaf(cZ,qz, qw)))).
    float cX[RPT], cY[RPT], cZ[RPT], cW[RPT];
#pragma unroll
    for (int i = 0; i < RPT; ++i) {
        float4 p = sm4[blockIdx.x * ROWS_PB + i];
        cX[i] = sfl(-2.0f * p.x);
        cY[i] = sfl(-2.0f * p.y);
        cZ[i] = sfl(-2.0f * p.z);
        cW[i] = sfl(p.w);
    }

    // ---- Bound: per-lane packed min over 4-cand slices of the octant's
    // first 256 cands (8 octants -> 2048-cand sample). Fold lanes ^32,^16
    // -> 128 minima/row (each the min of 16 distinct candidates).
    {
        unsigned pm[RPT];
#pragma unroll
        for (int i = 0; i < RPT; ++i) pm[i] = 0xFFFFFFFFu;
        const int b0 = w * (KQT * LANES);
#pragma unroll
        for (int k = 0; k < BNDI; ++k) {
            const int ci = b0 + k * LANES + lane;
            float4 q = sm4[ci];                 // coalesced, L1/L2-hot
#pragma unroll
            for (int i = 0; i < RPT; ++i) {
                float s = fmaf(cX[i], q.x,
                          fmaf(cY[i], q.y, fmaf(cZ[i], q.z, q.w)));
                pm[i] = umn(pm[i], pack_d2(s + cW[i], ci));  // canonical d2
            }
        }
#pragma unroll
        for (int i = 0; i < RPT; ++i) {
            pm[i] = umn(pm[i], (unsigned)__shfl_xor((int)pm[i], 32, 64));
            pm[i] = umn(pm[i], (unsigned)__shfl_xor((int)pm[i], 16, 64));
        }
        if (lane < 16) {
#pragma unroll
            for (int i = 0; i < RPT; ++i)
                bpart[i * BP + w * 16 + lane] = pm[i];
        }
    }
    __syncthreads();

    // Merge 128 minima/row -> bnd = 9th smallest (valid upper bound on the
    // row's true 9th: the 9 minima below it are 9 distinct candidates).
    if (t < 128) {                              // stage 1: 8 rows x 16 groups
        const int r1 = t & (ROWS_PB - 1);
        const int g = t >> 3;                   // 0..15
        unsigned s[KSEL];
#pragma unroll
        for (int k = 0; k < KSEL; ++k) s[k] = 0xFFFFFFFFu;
#pragma unroll
        for (int e = 0; e < 8; ++e)
            insert9(s, bpart[r1 * BP + g * 8 + e]);
#pragma unroll
        for (int k = 0; k < KSEL; ++k)
            scratch[r1 * SROW + g * KSEL + k] = s[k];
    }
    __syncthreads();
    if (t < 64) {                               // stage 2: 8 rows x 8 groups
        const int r1 = t & (ROWS_PB - 1);
        const int mg = t >> 3;                  // 0..7
        unsigned m[KSEL];
#pragma unroll
        for (int k = 0; k < KSEL; ++k) m[k] = 0xFFFFFFFFu;
#pragma unroll
        for (int e = 0; e < 2 * KSEL; ++e)
            insert9(m, scratch[r1 * SROW + (2 * mg) * KSEL + e]);
#pragma unroll
        for (int k = 0; k < KSEL; ++k)
            partS[r1 * PROW + mg * KSEL + k] = m[k];
    }
    __syncthreads();
    if (t < ROWS_PB) {                          // stage 3: 72 -> 9th
        unsigned m[KSEL];
#pragma unroll
        for (int k = 0; k < KSEL; ++k) m[k] = 0xFFFFFFFFu;
#pragma unroll
        for (int e = 0; e < 8 * KSEL; ++e)
            insert9(m, partS[t * PROW + e]);
        bnd[t] = m[0];
    }
    __syncthreads();

    // s-space screen bound: pack(d2)|idx <= b requires d2 <= bf where
    // bf = uint_as_float(b | IDX_MASK) (positive floats: uint order == float
    // order). d2 = fl(s + cW) <= bf  ==>  s <= (bf - cW) + ~ulp slack; the
    // relative loosening (on bf AND the difference) keeps sb a superset
    // bound under all cancellation cases. Extras are harmless.
    float sb[RPT];
#pragma unroll
    for (int i = 0; i < RPT; ++i) {
        float bfv = __uint_as_float(bnd[i] | IDX_MASK);
        float D = bfv - cW[i];
        sb[i] = sfl(D + (bfv + fabsf(D)) * 6.0e-7f + 1e-33f);
    }

    // ---- Scan: each wave sweeps its 1024-cand octant for all 8 rows ------
    unsigned base[RPT];
#pragma unroll
    for (int i = 0; i < RPT; ++i) base[i] = 0u;

    const int s0 = w * (KQT * LANES);
    const float4* __restrict__ qp = sm4 + s0 + lane;

    // Ping-pong depth 2. The qa refill on the final iteration over-reads one
    // float4 past the octant (w=7 lands in ss4 -- allocated workspace, value
    // never consumed) to keep the loop body branch-free.
    float4 qa = qp[0];
#pragma unroll 1
    for (int k0 = 0; k0 < KQT; k0 += 2) {
        float4 qb = qp[(k0 + 1) * LANES];
        {
            const int ci = s0 + k0 * LANES + lane;
            QUAD(0, qa, ci)
            QUAD(4, qa, ci)
        }
        qa = qp[(k0 + 2) * LANES];              // over-read on last iter: ok
        {
            const int ci = s0 + (k0 + 1) * LANES + lane;
            QUAD(0, qb, ci)
            QUAD(4, qb, ci)
        }
    }
    if (lane == 0) {
#pragma unroll
        for (int i = 0; i < RPT; ++i)
            wcnt[w * RPT + i] = umn(base[i], WCAP);
    }
    __syncthreads();                             // survivor lists complete

    // ---- Select: 64 tasks, each merges one (wave,row) list ---------------
    if (t < 64) {
        const int r1 = t & (ROWS_PB - 1);        // row
        const int wv = t >> 3;                   // 0..7 octant wave
        const int li = wv * RPT + r1;
        const unsigned n = wcnt[li];
        unsigned s[KSEL];
#pragma unroll
        for (int k = 0; k < KSEL; ++k) s[k] = 0xFFFFFFFFu;
        for (unsigned k = 0; k < n; ++k)
            insert9(s, wl[li * WCAP + k]);
#pragma unroll
        for (int k = 0; k < KSEL; ++k)
            partS[r1 * PROW + wv * KSEL + k] = s[k];
    }
    __syncthreads();

    if (t < ROWS_PB) {                          // final 72-merge + epilogue
        unsigned m[KSEL];
#pragma unroll
        for (int k = 0; k < KSEL; ++k) m[k] = 0xFFFFFFFFu;
#pragma unroll
        for (int e = 0; e < 8 * KSEL; ++e)
            insert9(m, partS[t * PROW + e]);

        // m[8] = global min (self, or identical-coordinate dup whose term is
        // 0 either way) -> dropped. m[0..7] = the 8 neighbors.
        const int gr = blockIdx.x * ROWS_PB + t;
        float4 pm4 = sm4[gr];
        float4 ps4 = ss4[gr];
        float acc = 0.0f;
#pragma unroll
        for (int k = 0; k < KNN; ++k) {
            int j = (int)(m[k] & IDX_MASK);
            float4 qm = sm4[j];
            float dx = pm4.x - qm.x, dy = pm4.y - qm.y, dz = pm4.z - qm.z;
            float d2 = fmaf(dx, dx, fmaf(dy, dy, dz * dz));
            float d = sqrtf(fmaxf(d2, EPS_F));
            float wgt = expf(-d);
            float4 qs = ss4[j];
            float ax = ps4.x - qs.x, ay = ps4.y - qs.y, az = ps4.z - qs.z;
            acc += wgt * (ax * ax + ay * ay + az * az);
        }
        red[t] = acc;
    }
    __syncthreads();
    if (t == 0) {
        float ssum = 0.0f;
#pragma unroll
        for (int i = 0; i < ROWS_PB; ++i) ssum += red[i];
        partial[blockIdx.x] = ssum;              // plain store
    }
}

// ---------------------------------------------------------------------------
// Kernel 3: reduce 1024 block partials -> scalar (cost ~0, proven R15;
// kept deterministic/order-identical so the output stays bit-exact).
// ---------------------------------------------------------------------------
__global__ __launch_bounds__(256) void reduce_k(
    const float* __restrict__ partial, float* __restrict__ out)
{
    __shared__ float sbuf[4];
    int t = threadIdx.x;
    float v = 0.0f;
    for (int i = t; i < NBLOCKS; i += 256) v += partial[i];
    for (int off = 32; off > 0; off >>= 1) v += __shfl_down(v, off);
    if ((t & 63) == 0) sbuf[t >> 6] = v;
    __syncthreads();
    if (t == 0) {
        float s = sbuf[0] + sbuf[1] + sbuf[2] + sbuf[3];
        out[0] = s * SCALE;
    }
}

// ---------------------------------------------------------------------------
extern "C" void kernel_launch(void* const* d_in, const int* in_sizes, int n_in,
                              void* d_out, int out_size, void* d_ws, size_t ws_size,
                              hipStream_t stream)
{
    const float* means = (const float*)d_in[0];
    const float* sh0   = (const float*)d_in[1];
    const int*   idxp  = (const int*)d_in[2];

    float4* sm4 = (float4*)d_ws;                 // 128 KB
    float4* ss4 = sm4 + NSAMPLE;                 // 128 KB
    float*  partial = (float*)(ss4 + NSAMPLE);   // 4 KB

    gather_k<<<NSAMPLE / 256, 256, 0, stream>>>(means, sh0, idxp, sm4, ss4);
    main_k<<<NBLOCKS, BLK, 0, stream>>>(sm4, ss4, partial);
    reduce_k<<<1, 256, 0, stream>>>(partial, (float*)d_out);
}